// Round 2
// baseline (672.539 us; speedup 1.0000x reference)
//
#include <hip/hip_runtime.h>
#include <hip/hip_bf16.h>

#define NN 20000
#define EE 640000

typedef __attribute__((ext_vector_type(8))) short bf16x8;
typedef __attribute__((ext_vector_type(4))) float f32x4;

__device__ __forceinline__ ushort f2b(float f) {
    __hip_bfloat16 h = __float2bfloat16(f);
    return *(ushort*)&h;
}
__device__ __forceinline__ float b2f(ushort u) {
    __hip_bfloat16 h = *(__hip_bfloat16*)&u;
    return __bfloat162float(h);
}

// ---------------- CSR build ----------------

__global__ void init_cnt_kernel(int* __restrict__ cnt, int n) {
    int i = blockIdx.x * 256 + threadIdx.x;
    if (i < n) cnt[i] = 0;
}

__global__ void hist_kernel(const int* __restrict__ col, int* __restrict__ cnt, int e) {
    int i = blockIdx.x * 256 + threadIdx.x;
    if (i < e) atomicAdd(&cnt[col[i]], 1);
}

__global__ void dinv_kernel(const int* __restrict__ cnt, float* __restrict__ dinv, int n) {
    int i = blockIdx.x * 256 + threadIdx.x;
    if (i < n) dinv[i] = rsqrtf((float)(cnt[i] + 1));  // +1 self-loop; always > 0
}

// single-block exclusive scan over n counts -> offs, cursor
__global__ void scan_kernel(const int* __restrict__ cnt, int* __restrict__ offs,
                            int* __restrict__ cursor, int n) {
    __shared__ int wsum[4];
    __shared__ int carry;
    int tid = threadIdx.x;
    int lane = tid & 63, w = tid >> 6;
    if (tid == 0) carry = 0;
    __syncthreads();
    for (int base = 0; base < n; base += 256) {
        int i = base + tid;
        int v = (i < n) ? cnt[i] : 0;
        int x = v;
        #pragma unroll
        for (int d = 1; d < 64; d <<= 1) {
            int y = __shfl_up(x, d, 64);
            if (lane >= d) x += y;
        }
        if (lane == 63) wsum[w] = x;
        __syncthreads();
        if (tid == 0) {
            int s = 0;
            #pragma unroll
            for (int k = 0; k < 4; ++k) { int t = wsum[k]; wsum[k] = s; s += t; }
        }
        __syncthreads();
        int excl = carry + wsum[w] + x - v;
        if (i < n) { offs[i] = excl; cursor[i] = excl; }
        __syncthreads();
        if (tid == 255) carry += wsum[3] + x;
        __syncthreads();
    }
}

__global__ void scatter_kernel(const int* __restrict__ row, const int* __restrict__ col,
                               const float* __restrict__ dinv, int* __restrict__ cursor,
                               int* __restrict__ csr_src, float* __restrict__ csr_nrm, int e) {
    int i = blockIdx.x * 256 + threadIdx.x;
    if (i >= e) return;
    int s = row[i], d = col[i];
    int pos = atomicAdd(&cursor[d], 1);
    csr_src[pos] = s;
    csr_nrm[pos] = dinv[s] * dinv[d];
}

// ---------------- chunkify: x [n][256] f32 -> cb [8][n][32] ----------------
__global__ __launch_bounds__(256) void chunkify_kernel(const float* __restrict__ x,
                                                       float* __restrict__ cb, int n) {
    int idx = blockIdx.x * 256 + threadIdx.x;  // over n*64 float4s
    if (idx >= n * 64) return;
    int node = idx >> 6;
    int q = idx & 63;
    float4 v = ((const float4*)(x + (size_t)node * 256))[q];
    int feat = q * 4;
    int c = feat >> 5, w = feat & 31;
    *(float4*)(cb + ((size_t)c * n + node) * 32 + w) = v;
}

// ---------------- weight prep: W [256][256] f32 -> Wt [256 col][768 kv] bf16 ----------------
// kv<256: hi(W[kv][col]); 256<=kv<512: lo(W[kv-256][col]); kv>=512: hi(W[kv-512][col])
__global__ __launch_bounds__(256) void wprep_kernel(const float* __restrict__ W,
                                                    ushort* __restrict__ Wt) {
    int col = blockIdx.x;
    for (int kv = threadIdx.x; kv < 768; kv += 256) {
        int k = kv & 255;
        float w = W[(size_t)k * 256 + col];
        ushort hi = f2b(w);
        ushort out = (kv < 256 || kv >= 512) ? hi : f2b(w - b2f(hi));
        Wt[(size_t)col * 768 + kv] = out;
    }
}

// ---------------- chunked aggregation ----------------
// cb: [8][n][32] f32. Block handles chunk (blockIdx.x&7) x 8 nodes. 32 lanes per node.
// Output: A2 [n][512] bf16 — cols 0..255 = hi, 256..511 = lo.
__global__ __launch_bounds__(256) void agg_kernel(
    const float* __restrict__ cb,
    const int* __restrict__ offs, const int* __restrict__ cnt,
    const int* __restrict__ csr_src, const float* __restrict__ csr_nrm,
    const float* __restrict__ dinv,
    ushort* __restrict__ a2, int n) {
    int chunk = blockIdx.x & 7;
    int node = (blockIdx.x >> 3) * 8 + (threadIdx.x >> 5);
    int lane = threadIdx.x & 31;
    if (node >= n) return;
    const float* slice = cb + (size_t)chunk * n * 32;
    float di = dinv[node];
    float acc = di * di * slice[(size_t)node * 32 + lane];
    int beg = offs[node], num = cnt[node];
    int j = 0;
    for (; j + 3 < num; j += 4) {
        int   s0 = __builtin_nontemporal_load(csr_src + beg + j);
        int   s1 = __builtin_nontemporal_load(csr_src + beg + j + 1);
        int   s2 = __builtin_nontemporal_load(csr_src + beg + j + 2);
        int   s3 = __builtin_nontemporal_load(csr_src + beg + j + 3);
        float m0 = __builtin_nontemporal_load(csr_nrm + beg + j);
        float m1 = __builtin_nontemporal_load(csr_nrm + beg + j + 1);
        float m2 = __builtin_nontemporal_load(csr_nrm + beg + j + 2);
        float m3 = __builtin_nontemporal_load(csr_nrm + beg + j + 3);
        float v0 = slice[(size_t)s0 * 32 + lane];
        float v1 = slice[(size_t)s1 * 32 + lane];
        float v2 = slice[(size_t)s2 * 32 + lane];
        float v3 = slice[(size_t)s3 * 32 + lane];
        acc = fmaf(m0, v0, acc);
        acc = fmaf(m1, v1, acc);
        acc = fmaf(m2, v2, acc);
        acc = fmaf(m3, v3, acc);
    }
    for (; j < num; ++j) {
        int   s0 = __builtin_nontemporal_load(csr_src + beg + j);
        float m0 = __builtin_nontemporal_load(csr_nrm + beg + j);
        acc = fmaf(m0, slice[(size_t)s0 * 32 + lane], acc);
    }
    int feat = chunk * 32 + lane;
    ushort hi = f2b(acc);
    float  lo = acc - b2f(hi);
    a2[(size_t)node * 512 + feat]       = hi;
    a2[(size_t)node * 512 + 256 + feat] = f2b(lo);
}

// ---------------- bf16 MFMA GEMM: C = A'' @ W'' (+bias, opt ReLU) ----------------
// A2 [n][512] bf16 (hi|lo), virtual K=768: kv<256 -> col kv (hi); 256..511 -> kv-256 (hi again);
// 512..767 -> kv-256 (lo). Wt [256][768] bf16 col-major-by-K. Tile: 64 rows x 128 cols, BK=64.
template<bool RELU, bool CHUNKED>
__global__ __launch_bounds__(256) void gemm_mfma_kernel(
    const ushort* __restrict__ A2, const ushort* __restrict__ Wt,
    const float* __restrict__ bias, float* __restrict__ C, int n) {
    __shared__ ushort Ast[64][72];
    __shared__ ushort Bst[128][72];
    int tid = threadIdx.x;
    int lane = tid & 63, wid = tid >> 6;
    int rowbase = blockIdx.x * 64;
    int colbase = blockIdx.y * 128;
    int wr = (wid >> 1) * 32, wc = (wid & 1) * 64;

    f32x4 zero = {0.f, 0.f, 0.f, 0.f};
    f32x4 acc[2][4];
    #pragma unroll
    for (int m = 0; m < 2; ++m)
        #pragma unroll
        for (int nn = 0; nn < 4; ++nn) acc[m][nn] = zero;

    int rA = tid >> 2, hA = tid & 3;     // A: 64 rows x 4 x 16-short segs
    int rB = tid >> 1, hB = tid & 1;     // B: 128 rows x 2 x 32-short segs
    int grA = min(rowbase + rA, n - 1);
    const ushort* aRow = A2 + (size_t)grA * 512;
    const ushort* bRow = Wt + (size_t)(colbase + rB) * 768;

    for (int kt = 0; kt < 12; ++kt) {
        int kv0 = kt * 64;
        int acol0 = (kv0 < 256) ? kv0 : kv0 - 256;
        #pragma unroll
        for (int q = 0; q < 2; ++q) {
            float4 av = *(const float4*)(aRow + acol0 + hA * 16 + q * 8);
            *(float4*)(&Ast[rA][hA * 16 + q * 8]) = av;
        }
        #pragma unroll
        for (int q = 0; q < 4; ++q) {
            float4 bv = *(const float4*)(bRow + kv0 + hB * 32 + q * 8);
            *(float4*)(&Bst[rB][hB * 32 + q * 8]) = bv;
        }
        __syncthreads();
        #pragma unroll
        for (int kk = 0; kk < 2; ++kk) {
            int ko = kk * 32 + (lane >> 4) * 8;
            bf16x8 af[2], bf[4];
            #pragma unroll
            for (int m = 0; m < 2; ++m)
                af[m] = *(const bf16x8*)&Ast[wr + m * 16 + (lane & 15)][ko];
            #pragma unroll
            for (int nn = 0; nn < 4; ++nn)
                bf[nn] = *(const bf16x8*)&Bst[wc + nn * 16 + (lane & 15)][ko];
            #pragma unroll
            for (int m = 0; m < 2; ++m)
                #pragma unroll
                for (int nn = 0; nn < 4; ++nn)
                    acc[m][nn] = __builtin_amdgcn_mfma_f32_16x16x32_bf16(
                        af[m], bf[nn], acc[m][nn], 0, 0, 0);
        }
        __syncthreads();
    }

    #pragma unroll
    for (int nn = 0; nn < 4; ++nn) {
        int col = colbase + wc + nn * 16 + (lane & 15);
        float bv = bias[col];
        #pragma unroll
        for (int m = 0; m < 2; ++m) {
            int grow0 = rowbase + wr + m * 16 + ((lane >> 4) << 2);
            f32x4 v = acc[m][nn];
            #pragma unroll
            for (int r = 0; r < 4; ++r) {
                int row = grow0 + r;
                if (row < n) {
                    float val = v[r] + bv;
                    if (RELU) val = fmaxf(val, 0.f);
                    if (CHUNKED)
                        C[((size_t)(col >> 5) * n + row) * 32 + (col & 31)] = val;
                    else
                        C[(size_t)row * 256 + col] = val;
                }
            }
        }
    }
}

// ---------------- final projection: out[i] = h3[i,:] . Wout + bout ----------------
__global__ __launch_bounds__(256) void out_kernel(
    const float* __restrict__ h3, const float* __restrict__ Wout,
    const float* __restrict__ bout, float* __restrict__ out, int n) {
    int node = blockIdx.x * 4 + (threadIdx.x >> 6);
    int lane = threadIdx.x & 63;
    if (node >= n) return;
    float4 v = ((const float4*)(h3 + (size_t)node * 256))[lane];
    float4 w = ((const float4*)Wout)[lane];
    float sum = v.x * w.x + v.y * w.y + v.z * w.z + v.w * w.w;
    #pragma unroll
    for (int d = 32; d > 0; d >>= 1) sum += __shfl_down(sum, d, 64);
    if (lane == 0) out[node] = sum + bout[0];
}

extern "C" void kernel_launch(void* const* d_in, const int* in_sizes, int n_in,
                              void* d_out, int out_size, void* d_ws, size_t ws_size,
                              hipStream_t stream) {
    const int n = NN, e = EE;
    const float* x    = (const float*)d_in[0];
    const int*   eidx = (const int*)d_in[1];
    const float* W1   = (const float*)d_in[2];
    const float* b1   = (const float*)d_in[3];
    const float* Wh   = (const float*)d_in[4];
    const float* bh   = (const float*)d_in[5];
    const float* W2   = (const float*)d_in[6];
    const float* b2   = (const float*)d_in[7];
    const float* Wout = (const float*)d_in[8];
    const float* bout = (const float*)d_in[9];
    const int* row = eidx;        // sources
    const int* col = eidx + e;    // destinations

    char* ws = (char*)d_ws;
    int*    cnt     = (int*)ws;    ws += (size_t)n * 4;
    int*    offs    = (int*)ws;    ws += (size_t)n * 4;
    int*    cursor  = (int*)ws;    ws += (size_t)n * 4;
    float*  dinv    = (float*)ws;  ws += (size_t)n * 4;
    int*    csr_src = (int*)ws;    ws += (size_t)e * 4;
    float*  csr_nrm = (float*)ws;  ws += (size_t)e * 4;
    float*  cb      = (float*)ws;  ws += (size_t)n * 256 * 4;   // chunked h  [8][n][32]
    ushort* a2      = (ushort*)ws; ws += (size_t)n * 512 * 2;   // A'' hi|lo  [n][512]
    ushort* wt1     = (ushort*)ws; ws += (size_t)256 * 768 * 2;
    ushort* wt2     = (ushort*)ws; ws += (size_t)256 * 768 * 2;
    ushort* wt3     = (ushort*)ws; ws += (size_t)256 * 768 * 2;

    float* outv = (float*)d_out;
    float* h3   = (float*)d_out + n;

    int nb_n = (n + 255) / 256;
    int nb_e = (e + 255) / 256;

    // CSR build
    init_cnt_kernel<<<nb_n, 256, 0, stream>>>(cnt, n);
    hist_kernel<<<nb_e, 256, 0, stream>>>(col, cnt, e);
    dinv_kernel<<<nb_n, 256, 0, stream>>>(cnt, dinv, n);
    scan_kernel<<<1, 256, 0, stream>>>(cnt, offs, cursor, n);
    scatter_kernel<<<nb_e, 256, 0, stream>>>(row, col, dinv, cursor, csr_src, csr_nrm, e);

    // weight prep + chunkify x
    wprep_kernel<<<256, 256, 0, stream>>>(W1, wt1);
    wprep_kernel<<<256, 256, 0, stream>>>(Wh, wt2);
    wprep_kernel<<<256, 256, 0, stream>>>(W2, wt3);
    chunkify_kernel<<<(n * 64 + 255) / 256, 256, 0, stream>>>(x, cb, n);

    int agrid = (n / 8) * 8;          // 20000 blocks, chunk = blockIdx & 7
    dim3 ggrid((n + 63) / 64, 2);

    // layer 1
    agg_kernel<<<agrid, 256, 0, stream>>>(cb, offs, cnt, csr_src, csr_nrm, dinv, a2, n);
    gemm_mfma_kernel<true, true><<<ggrid, 256, 0, stream>>>(a2, wt1, b1, cb, n);
    // layer 2
    agg_kernel<<<agrid, 256, 0, stream>>>(cb, offs, cnt, csr_src, csr_nrm, dinv, a2, n);
    gemm_mfma_kernel<true, true><<<ggrid, 256, 0, stream>>>(a2, wt2, bh, cb, n);
    // layer 3 -> h3 (row-major f32, straight into d_out)
    agg_kernel<<<agrid, 256, 0, stream>>>(cb, offs, cnt, csr_src, csr_nrm, dinv, a2, n);
    gemm_mfma_kernel<false, false><<<ggrid, 256, 0, stream>>>(a2, wt3, b2, h3, n);
    // decoder
    out_kernel<<<(n + 3) / 4, 256, 0, stream>>>(h3, Wout, bout, outv, n);
}

// Round 3
// 416.154 us; speedup vs baseline: 1.6161x; 1.6161x over previous
//
#include <hip/hip_runtime.h>
#include <hip/hip_bf16.h>

#define NN 20000
#define EE 640000

typedef __attribute__((ext_vector_type(8))) short bf16x8;
typedef __attribute__((ext_vector_type(4))) float f32x4;

__device__ __forceinline__ ushort f2b(float f) {
    __hip_bfloat16 h = __float2bfloat16(f);
    return *(ushort*)&h;
}
__device__ __forceinline__ float b2f(ushort u) {
    __hip_bfloat16 h = *(__hip_bfloat16*)&u;
    return __bfloat162float(h);
}

// ---------------- CSR build ----------------

__global__ void init_cnt_kernel(int* __restrict__ cnt, int n) {
    int i = blockIdx.x * 256 + threadIdx.x;
    if (i < n) cnt[i] = 0;
}

__global__ void hist_kernel(const int* __restrict__ col, int* __restrict__ cnt, int e) {
    int i = blockIdx.x * 256 + threadIdx.x;
    if (i < e) atomicAdd(&cnt[col[i]], 1);
}

__global__ void dinv_kernel(const int* __restrict__ cnt, float* __restrict__ dinv, int n) {
    int i = blockIdx.x * 256 + threadIdx.x;
    if (i < n) dinv[i] = rsqrtf((float)(cnt[i] + 1));  // +1 self-loop; always > 0
}

// single-block exclusive scan over n counts -> offs, cursor
__global__ void scan_kernel(const int* __restrict__ cnt, int* __restrict__ offs,
                            int* __restrict__ cursor, int n) {
    __shared__ int wsum[4];
    __shared__ int carry;
    int tid = threadIdx.x;
    int lane = tid & 63, w = tid >> 6;
    if (tid == 0) carry = 0;
    __syncthreads();
    for (int base = 0; base < n; base += 256) {
        int i = base + tid;
        int v = (i < n) ? cnt[i] : 0;
        int x = v;
        #pragma unroll
        for (int d = 1; d < 64; d <<= 1) {
            int y = __shfl_up(x, d, 64);
            if (lane >= d) x += y;
        }
        if (lane == 63) wsum[w] = x;
        __syncthreads();
        if (tid == 0) {
            int s = 0;
            #pragma unroll
            for (int k = 0; k < 4; ++k) { int t = wsum[k]; wsum[k] = s; s += t; }
        }
        __syncthreads();
        int excl = carry + wsum[w] + x - v;
        if (i < n) { offs[i] = excl; cursor[i] = excl; }
        __syncthreads();
        if (tid == 255) carry += wsum[3] + x;
        __syncthreads();
    }
}

__global__ void scatter_kernel(const int* __restrict__ row, const int* __restrict__ col,
                               const float* __restrict__ dinv, int* __restrict__ cursor,
                               int* __restrict__ csr_src, float* __restrict__ csr_nrm, int e) {
    int i = blockIdx.x * 256 + threadIdx.x;
    if (i >= e) return;
    int s = row[i], d = col[i];
    int pos = atomicAdd(&cursor[d], 1);
    csr_src[pos] = s;
    csr_nrm[pos] = dinv[s] * dinv[d];
}

// ---------------- weight prep: W [256][256] f32 -> Wt [256 col][768 kv] bf16 ----------------
__global__ __launch_bounds__(256) void wprep_kernel(const float* __restrict__ W,
                                                    ushort* __restrict__ Wt) {
    int col = blockIdx.x;
    for (int kv = threadIdx.x; kv < 768; kv += 256) {
        int k = kv & 255;
        float w = W[(size_t)k * 256 + col];
        ushort hi = f2b(w);
        ushort out = (kv < 256 || kv >= 512) ? hi : f2b(w - b2f(hi));
        Wt[(size_t)col * 768 + kv] = out;
    }
}

// ---------------- chunked aggregation, float4 gathers, 8 edges in flight ----------------
// h row-major [n][256]. Block: chunk = bid&7 (32 feats), 4 waves = 4 nodes.
// Lane: esub = lane>>3 (edge in group of 8), fsub = lane&7 (float4 within chunk).
// Output: a2 [n][512] bf16 — cols 0..255 hi, 256..511 lo.
__global__ __launch_bounds__(256) void agg_kernel(
    const float* __restrict__ h,
    const int* __restrict__ offs, const int* __restrict__ cnt,
    const int* __restrict__ csr_src, const float* __restrict__ csr_nrm,
    const float* __restrict__ dinv,
    ushort* __restrict__ a2, int n) {
    int chunk = blockIdx.x & 7;
    int node = (blockIdx.x >> 3) * 4 + (threadIdx.x >> 6);
    if (node >= n) return;
    int lane = threadIdx.x & 63;
    int esub = lane >> 3;
    int fsub = lane & 7;
    const float* base = h + chunk * 32 + fsub * 4;

    float4 acc = {0.f, 0.f, 0.f, 0.f};
    int beg = offs[node], num = cnt[node];

    int j = 0;
    for (; j + 16 <= num; j += 16) {
        int j0 = beg + j + esub;
        int j1 = j0 + 8;
        int   s0 = csr_src[j0], s1 = csr_src[j1];
        float m0 = csr_nrm[j0], m1 = csr_nrm[j1];
        float4 v0 = *(const float4*)(base + (size_t)s0 * 256);
        float4 v1 = *(const float4*)(base + (size_t)s1 * 256);
        acc.x = fmaf(m0, v0.x, acc.x); acc.y = fmaf(m0, v0.y, acc.y);
        acc.z = fmaf(m0, v0.z, acc.z); acc.w = fmaf(m0, v0.w, acc.w);
        acc.x = fmaf(m1, v1.x, acc.x); acc.y = fmaf(m1, v1.y, acc.y);
        acc.z = fmaf(m1, v1.z, acc.z); acc.w = fmaf(m1, v1.w, acc.w);
    }
    if (j < num) {
        int jj = j + esub;
        bool valid = jj < num;
        int   s0 = valid ? csr_src[beg + jj] : node;
        float m0 = valid ? csr_nrm[beg + jj] : 0.f;
        float4 v0 = *(const float4*)(base + (size_t)s0 * 256);
        acc.x = fmaf(m0, v0.x, acc.x); acc.y = fmaf(m0, v0.y, acc.y);
        acc.z = fmaf(m0, v0.z, acc.z); acc.w = fmaf(m0, v0.w, acc.w);
        if (j + 8 < num) {
            int jk = j + 8 + esub;
            bool v2 = jk < num;
            int   s1 = v2 ? csr_src[beg + jk] : node;
            float m1 = v2 ? csr_nrm[beg + jk] : 0.f;
            float4 v1 = *(const float4*)(base + (size_t)s1 * 256);
            acc.x = fmaf(m1, v1.x, acc.x); acc.y = fmaf(m1, v1.y, acc.y);
            acc.z = fmaf(m1, v1.z, acc.z); acc.w = fmaf(m1, v1.w, acc.w);
        }
    }

    // all-reduce across the 8 esub groups (xor butterfly over lanes 8,16,32)
    #pragma unroll
    for (int d = 8; d < 64; d <<= 1) {
        acc.x += __shfl_xor(acc.x, d, 64);
        acc.y += __shfl_xor(acc.y, d, 64);
        acc.z += __shfl_xor(acc.z, d, 64);
        acc.w += __shfl_xor(acc.w, d, 64);
    }

    if (esub == 0) {   // lanes 0..7 hold fsub 0..7
        float di = dinv[node];
        float sn = di * di;
        float4 self = *(const float4*)(base + (size_t)node * 256);
        acc.x = fmaf(sn, self.x, acc.x); acc.y = fmaf(sn, self.y, acc.y);
        acc.z = fmaf(sn, self.z, acc.z); acc.w = fmaf(sn, self.w, acc.w);
        int feat = chunk * 32 + fsub * 4;
        ushort4 hi, lo;
        hi.x = f2b(acc.x); lo.x = f2b(acc.x - b2f(hi.x));
        hi.y = f2b(acc.y); lo.y = f2b(acc.y - b2f(hi.y));
        hi.z = f2b(acc.z); lo.z = f2b(acc.z - b2f(hi.z));
        hi.w = f2b(acc.w); lo.w = f2b(acc.w - b2f(hi.w));
        *(ushort4*)(a2 + (size_t)node * 512 + feat)       = hi;
        *(ushort4*)(a2 + (size_t)node * 512 + 256 + feat) = lo;
    }
}

// ---------------- bf16 MFMA GEMM: C = A'' @ W'' (+bias, opt ReLU), C row-major f32 ----------------
template<bool RELU>
__global__ __launch_bounds__(256) void gemm_mfma_kernel(
    const ushort* __restrict__ A2, const ushort* __restrict__ Wt,
    const float* __restrict__ bias, float* __restrict__ C, int n) {
    __shared__ ushort Ast[64][72];
    __shared__ ushort Bst[128][72];
    int tid = threadIdx.x;
    int lane = tid & 63, wid = tid >> 6;
    int rowbase = blockIdx.x * 64;
    int colbase = blockIdx.y * 128;
    int wr = (wid >> 1) * 32, wc = (wid & 1) * 64;

    f32x4 zero = {0.f, 0.f, 0.f, 0.f};
    f32x4 acc[2][4];
    #pragma unroll
    for (int m = 0; m < 2; ++m)
        #pragma unroll
        for (int nn = 0; nn < 4; ++nn) acc[m][nn] = zero;

    int rA = tid >> 2, hA = tid & 3;
    int rB = tid >> 1, hB = tid & 1;
    int grA = min(rowbase + rA, n - 1);
    const ushort* aRow = A2 + (size_t)grA * 512;
    const ushort* bRow = Wt + (size_t)(colbase + rB) * 768;

    for (int kt = 0; kt < 12; ++kt) {
        int kv0 = kt * 64;
        int acol0 = (kv0 < 256) ? kv0 : kv0 - 256;
        #pragma unroll
        for (int q = 0; q < 2; ++q) {
            float4 av = *(const float4*)(aRow + acol0 + hA * 16 + q * 8);
            *(float4*)(&Ast[rA][hA * 16 + q * 8]) = av;
        }
        #pragma unroll
        for (int q = 0; q < 4; ++q) {
            float4 bv = *(const float4*)(bRow + kv0 + hB * 32 + q * 8);
            *(float4*)(&Bst[rB][hB * 32 + q * 8]) = bv;
        }
        __syncthreads();
        #pragma unroll
        for (int kk = 0; kk < 2; ++kk) {
            int ko = kk * 32 + (lane >> 4) * 8;
            bf16x8 af[2], bf[4];
            #pragma unroll
            for (int m = 0; m < 2; ++m)
                af[m] = *(const bf16x8*)&Ast[wr + m * 16 + (lane & 15)][ko];
            #pragma unroll
            for (int nn = 0; nn < 4; ++nn)
                bf[nn] = *(const bf16x8*)&Bst[wc + nn * 16 + (lane & 15)][ko];
            #pragma unroll
            for (int m = 0; m < 2; ++m)
                #pragma unroll
                for (int nn = 0; nn < 4; ++nn)
                    acc[m][nn] = __builtin_amdgcn_mfma_f32_16x16x32_bf16(
                        af[m], bf[nn], acc[m][nn], 0, 0, 0);
        }
        __syncthreads();
    }

    #pragma unroll
    for (int nn = 0; nn < 4; ++nn) {
        int col = colbase + wc + nn * 16 + (lane & 15);
        float bv = bias[col];
        #pragma unroll
        for (int m = 0; m < 2; ++m) {
            int grow0 = rowbase + wr + m * 16 + ((lane >> 4) << 2);
            f32x4 v = acc[m][nn];
            #pragma unroll
            for (int r = 0; r < 4; ++r) {
                int row = grow0 + r;
                if (row < n) {
                    float val = v[r] + bv;
                    if (RELU) val = fmaxf(val, 0.f);
                    C[(size_t)row * 256 + col] = val;
                }
            }
        }
    }
}

// ---------------- final projection: out[i] = h3[i,:] . Wout + bout ----------------
__global__ __launch_bounds__(256) void out_kernel(
    const float* __restrict__ h3, const float* __restrict__ Wout,
    const float* __restrict__ bout, float* __restrict__ out, int n) {
    int node = blockIdx.x * 4 + (threadIdx.x >> 6);
    int lane = threadIdx.x & 63;
    if (node >= n) return;
    float4 v = ((const float4*)(h3 + (size_t)node * 256))[lane];
    float4 w = ((const float4*)Wout)[lane];
    float sum = v.x * w.x + v.y * w.y + v.z * w.z + v.w * w.w;
    #pragma unroll
    for (int d = 32; d > 0; d >>= 1) sum += __shfl_down(sum, d, 64);
    if (lane == 0) out[node] = sum + bout[0];
}

extern "C" void kernel_launch(void* const* d_in, const int* in_sizes, int n_in,
                              void* d_out, int out_size, void* d_ws, size_t ws_size,
                              hipStream_t stream) {
    const int n = NN, e = EE;
    const float* x    = (const float*)d_in[0];
    const int*   eidx = (const int*)d_in[1];
    const float* W1   = (const float*)d_in[2];
    const float* b1   = (const float*)d_in[3];
    const float* Wh   = (const float*)d_in[4];
    const float* bh   = (const float*)d_in[5];
    const float* W2   = (const float*)d_in[6];
    const float* b2   = (const float*)d_in[7];
    const float* Wout = (const float*)d_in[8];
    const float* bout = (const float*)d_in[9];
    const int* row = eidx;        // sources
    const int* col = eidx + e;    // destinations

    char* ws = (char*)d_ws;
    int*    cnt     = (int*)ws;    ws += (size_t)n * 4;
    int*    offs    = (int*)ws;    ws += (size_t)n * 4;
    int*    cursor  = (int*)ws;    ws += (size_t)n * 4;
    float*  dinv    = (float*)ws;  ws += (size_t)n * 4;
    int*    csr_src = (int*)ws;    ws += (size_t)e * 4;
    float*  csr_nrm = (float*)ws;  ws += (size_t)e * 4;
    float*  buf     = (float*)ws;  ws += (size_t)n * 256 * 4;   // hidden state [n][256]
    ushort* a2      = (ushort*)ws; ws += (size_t)n * 512 * 2;   // A'' hi|lo [n][512]
    ushort* wt1     = (ushort*)ws; ws += (size_t)256 * 768 * 2;
    ushort* wt2     = (ushort*)ws; ws += (size_t)256 * 768 * 2;
    ushort* wt3     = (ushort*)ws; ws += (size_t)256 * 768 * 2;

    float* outv = (float*)d_out;
    float* h3   = (float*)d_out + n;

    int nb_n = (n + 255) / 256;
    int nb_e = (e + 255) / 256;

    // CSR build
    init_cnt_kernel<<<nb_n, 256, 0, stream>>>(cnt, n);
    hist_kernel<<<nb_e, 256, 0, stream>>>(col, cnt, e);
    dinv_kernel<<<nb_n, 256, 0, stream>>>(cnt, dinv, n);
    scan_kernel<<<1, 256, 0, stream>>>(cnt, offs, cursor, n);
    scatter_kernel<<<nb_e, 256, 0, stream>>>(row, col, dinv, cursor, csr_src, csr_nrm, e);

    // weight prep
    wprep_kernel<<<256, 256, 0, stream>>>(W1, wt1);
    wprep_kernel<<<256, 256, 0, stream>>>(Wh, wt2);
    wprep_kernel<<<256, 256, 0, stream>>>(W2, wt3);

    int agrid = (n / 4) * 8;          // 40000 blocks: chunk = bid&7, nodegroup = bid>>3
    dim3 ggrid((n + 63) / 64, 2);

    // layer 1 (agg reads x directly)
    agg_kernel<<<agrid, 256, 0, stream>>>(x, offs, cnt, csr_src, csr_nrm, dinv, a2, n);
    gemm_mfma_kernel<true><<<ggrid, 256, 0, stream>>>(a2, wt1, b1, buf, n);
    // layer 2
    agg_kernel<<<agrid, 256, 0, stream>>>(buf, offs, cnt, csr_src, csr_nrm, dinv, a2, n);
    gemm_mfma_kernel<true><<<ggrid, 256, 0, stream>>>(a2, wt2, bh, buf, n);
    // layer 3 -> h3 straight into d_out
    agg_kernel<<<agrid, 256, 0, stream>>>(buf, offs, cnt, csr_src, csr_nrm, dinv, a2, n);
    gemm_mfma_kernel<false><<<ggrid, 256, 0, stream>>>(a2, wt3, b2, h3, n);
    // decoder
    out_kernel<<<(n + 3) / 4, 256, 0, stream>>>(h3, Wout, bout, outv, n);
}

// Round 4
// 380.769 us; speedup vs baseline: 1.7663x; 1.0929x over previous
//
#include <hip/hip_runtime.h>
#include <hip/hip_bf16.h>

#define NN 20000
#define EE 640000

typedef __attribute__((ext_vector_type(8))) short bf16x8;
typedef __attribute__((ext_vector_type(4))) float f32x4;

__device__ __forceinline__ ushort f2b(float f) {
    __hip_bfloat16 h = __float2bfloat16(f);
    return *(ushort*)&h;
}
__device__ __forceinline__ float b2f(ushort u) {
    __hip_bfloat16 h = *(__hip_bfloat16*)&u;
    return __bfloat162float(h);
}

// ---------------- CSR build ----------------

__global__ void init_cnt_kernel(int* __restrict__ cnt, int n) {
    int i = blockIdx.x * 256 + threadIdx.x;
    if (i < n) cnt[i] = 0;
}

__global__ void hist_kernel(const int* __restrict__ col, int* __restrict__ cnt, int e) {
    int i = blockIdx.x * 256 + threadIdx.x;
    if (i < e) atomicAdd(&cnt[col[i]], 1);
}

__global__ void dinv_kernel(const int* __restrict__ cnt, float* __restrict__ dinv, int n) {
    int i = blockIdx.x * 256 + threadIdx.x;
    if (i < n) dinv[i] = rsqrtf((float)(cnt[i] + 1));  // +1 self-loop; always > 0
}

// in-block exclusive scan helper (256 threads)
__device__ __forceinline__ int block_exscan(int v) {
    __shared__ int wsum[4];
    int tid = threadIdx.x, lane = tid & 63, w = tid >> 6;
    int x = v;
    #pragma unroll
    for (int d = 1; d < 64; d <<= 1) {
        int y = __shfl_up(x, d, 64);
        if (lane >= d) x += y;
    }
    if (lane == 63) wsum[w] = x;
    __syncthreads();
    if (tid == 0) {
        int s = 0;
        #pragma unroll
        for (int k = 0; k < 4; ++k) { int t = wsum[k]; wsum[k] = s; s += t; }
    }
    __syncthreads();
    return wsum[w] + x - v;
}

// phase 1: per-block local exclusive scan + block totals
__global__ __launch_bounds__(256) void scan_p1_kernel(const int* __restrict__ cnt,
                                                      int* __restrict__ offs,
                                                      int* __restrict__ bsum, int n) {
    int i = blockIdx.x * 256 + threadIdx.x;
    int v = (i < n) ? cnt[i] : 0;
    int e = block_exscan(v);
    if (i < n) offs[i] = e;
    if (threadIdx.x == 255) bsum[blockIdx.x] = e + v;
}

// phase 2: scan the block totals (nblk <= 256)
__global__ __launch_bounds__(256) void scan_p2_kernel(int* __restrict__ bsum, int nblk) {
    int t = threadIdx.x;
    int v = (t < nblk) ? bsum[t] : 0;
    int e = block_exscan(v);
    if (t < nblk) bsum[t] = e;
}

// phase 3: add block offsets
__global__ __launch_bounds__(256) void scan_p3_kernel(int* __restrict__ offs,
                                                      const int* __restrict__ bsum,
                                                      int* __restrict__ cursor, int n) {
    int i = blockIdx.x * 256 + threadIdx.x;
    if (i < n) {
        int o = offs[i] + bsum[blockIdx.x];
        offs[i] = o;
        cursor[i] = o;
    }
}

__global__ void scatter_kernel(const int* __restrict__ row, const int* __restrict__ col,
                               const float* __restrict__ dinv, int* __restrict__ cursor,
                               int2* __restrict__ pair, int e) {
    int i = blockIdx.x * 256 + threadIdx.x;
    if (i >= e) return;
    int s = row[i], d = col[i];
    int pos = atomicAdd(&cursor[d], 1);
    int2 p;
    p.x = s;
    p.y = __float_as_int(dinv[s] * dinv[d]);
    pair[pos] = p;
}

// ---------------- weight prep: W [256][256] f32 -> Wt [256 col][768 kv] bf16 ----------------
__global__ __launch_bounds__(256) void wprep_kernel(const float* __restrict__ W,
                                                    ushort* __restrict__ Wt) {
    int col = blockIdx.x;
    for (int kv = threadIdx.x; kv < 768; kv += 256) {
        int k = kv & 255;
        float w = W[(size_t)k * 256 + col];
        ushort hi = f2b(w);
        ushort out = (kv < 256 || kv >= 512) ? hi : f2b(w - b2f(hi));
        Wt[(size_t)col * 768 + kv] = out;
    }
}

// ---------------- aggregation v3: 8 nodes per wave, no cross-lane reduce ----------------
// h row-major [n][256]. Block: chunk = bid&7 (32 feats), 4 waves x 8 nodes = 32 nodes.
// Lane: g = lane>>3 (node subgroup), fsub = lane&7 (float4 within chunk).
// Output: a2 [n][512] bf16 — cols 0..255 hi, 256..511 lo.
__global__ __launch_bounds__(256) void agg_kernel(
    const float* __restrict__ h,
    const int* __restrict__ offs, const int* __restrict__ cnt,
    const int2* __restrict__ pair,
    const float* __restrict__ dinv,
    ushort* __restrict__ a2, int n) {
    int chunk = blockIdx.x & 7;
    int wid = threadIdx.x >> 6;
    int lane = threadIdx.x & 63;
    int g = lane >> 3, fsub = lane & 7;
    int node = (blockIdx.x >> 3) * 32 + wid * 8 + g;   // n % 32 == 0, always in range
    const float* base = h + chunk * 32 + fsub * 4;

    int beg = offs[node], num = cnt[node];
    int maxnum = num;
    #pragma unroll
    for (int d = 8; d < 64; d <<= 1)
        maxnum = max(maxnum, __shfl_xor(maxnum, d, 64));

    float4 acc = {0.f, 0.f, 0.f, 0.f};
    for (int j = 0; j < maxnum; j += 2) {
        bool p0 = j < num, p1 = j + 1 < num;
        int i0 = p0 ? beg + j : 0;
        int i1 = p1 ? beg + j + 1 : 0;
        int2 e0 = pair[i0];
        int2 e1 = pair[i1];
        float m0 = p0 ? __int_as_float(e0.y) : 0.f;
        float m1 = p1 ? __int_as_float(e1.y) : 0.f;
        float4 v0 = *(const float4*)(base + (size_t)e0.x * 256);
        float4 v1 = *(const float4*)(base + (size_t)e1.x * 256);
        acc.x = fmaf(m0, v0.x, acc.x); acc.y = fmaf(m0, v0.y, acc.y);
        acc.z = fmaf(m0, v0.z, acc.z); acc.w = fmaf(m0, v0.w, acc.w);
        acc.x = fmaf(m1, v1.x, acc.x); acc.y = fmaf(m1, v1.y, acc.y);
        acc.z = fmaf(m1, v1.z, acc.z); acc.w = fmaf(m1, v1.w, acc.w);
    }

    float di = dinv[node];
    float sn = di * di;
    float4 self = *(const float4*)(base + (size_t)node * 256);
    acc.x = fmaf(sn, self.x, acc.x); acc.y = fmaf(sn, self.y, acc.y);
    acc.z = fmaf(sn, self.z, acc.z); acc.w = fmaf(sn, self.w, acc.w);

    int feat = chunk * 32 + fsub * 4;
    ushort4 hi, lo;
    hi.x = f2b(acc.x); lo.x = f2b(acc.x - b2f(hi.x));
    hi.y = f2b(acc.y); lo.y = f2b(acc.y - b2f(hi.y));
    hi.z = f2b(acc.z); lo.z = f2b(acc.z - b2f(hi.z));
    hi.w = f2b(acc.w); lo.w = f2b(acc.w - b2f(hi.w));
    *(ushort4*)(a2 + (size_t)node * 512 + feat)       = hi;
    *(ushort4*)(a2 + (size_t)node * 512 + 256 + feat) = lo;
}

// ---------------- bf16 MFMA GEMM: C = A'' @ W'' (+bias, opt ReLU), 128x128 tile ----------------
template<bool RELU>
__global__ __launch_bounds__(256) void gemm_mfma_kernel(
    const ushort* __restrict__ A2, const ushort* __restrict__ Wt,
    const float* __restrict__ bias, float* __restrict__ C, int n) {
    __shared__ ushort Ast[128][72];
    __shared__ ushort Bst[128][72];
    int tid = threadIdx.x;
    int lane = tid & 63, wid = tid >> 6;
    int rowbase = blockIdx.x * 128;
    int colbase = blockIdx.y * 128;
    int awr = (wid >> 1) * 64;
    int bwc = (wid & 1) * 64;

    f32x4 zero = {0.f, 0.f, 0.f, 0.f};
    f32x4 acc[4][4];
    #pragma unroll
    for (int m = 0; m < 4; ++m)
        #pragma unroll
        for (int nn = 0; nn < 4; ++nn) acc[m][nn] = zero;

    int rS = tid >> 1;                 // 0..127
    int sBase = (tid & 1) * 32;        // half-row of 64 shorts
    int grA = min(rowbase + rS, n - 1);
    const ushort* aRow = A2 + (size_t)grA * 512;
    const ushort* bRow = Wt + (size_t)(colbase + rS) * 768;

    for (int kt = 0; kt < 12; ++kt) {
        int kv0 = kt * 64;
        int acol0 = (kv0 < 256) ? kv0 : kv0 - 256;
        #pragma unroll
        for (int q = 0; q < 4; ++q)
            *(float4*)(&Ast[rS][sBase + q * 8]) =
                *(const float4*)(aRow + acol0 + sBase + q * 8);
        #pragma unroll
        for (int q = 0; q < 4; ++q)
            *(float4*)(&Bst[rS][sBase + q * 8]) =
                *(const float4*)(bRow + kv0 + sBase + q * 8);
        __syncthreads();
        #pragma unroll
        for (int kk = 0; kk < 2; ++kk) {
            int ko = kk * 32 + (lane >> 4) * 8;
            bf16x8 af[4], bf[4];
            #pragma unroll
            for (int m = 0; m < 4; ++m)
                af[m] = *(const bf16x8*)&Ast[awr + m * 16 + (lane & 15)][ko];
            #pragma unroll
            for (int nn = 0; nn < 4; ++nn)
                bf[nn] = *(const bf16x8*)&Bst[bwc + nn * 16 + (lane & 15)][ko];
            #pragma unroll
            for (int m = 0; m < 4; ++m)
                #pragma unroll
                for (int nn = 0; nn < 4; ++nn)
                    acc[m][nn] = __builtin_amdgcn_mfma_f32_16x16x32_bf16(
                        af[m], bf[nn], acc[m][nn], 0, 0, 0);
        }
        __syncthreads();
    }

    #pragma unroll
    for (int nn = 0; nn < 4; ++nn) {
        int col = colbase + bwc + nn * 16 + (lane & 15);
        float bv = bias[col];
        #pragma unroll
        for (int m = 0; m < 4; ++m) {
            int grow0 = rowbase + awr + m * 16 + ((lane >> 4) << 2);
            f32x4 v = acc[m][nn];
            #pragma unroll
            for (int r = 0; r < 4; ++r) {
                int row = grow0 + r;
                if (row < n) {
                    float val = v[r] + bv;
                    if (RELU) val = fmaxf(val, 0.f);
                    C[(size_t)row * 256 + col] = val;
                }
            }
        }
    }
}

// ---------------- final projection: out[i] = h3[i,:] . Wout + bout ----------------
__global__ __launch_bounds__(256) void out_kernel(
    const float* __restrict__ h3, const float* __restrict__ Wout,
    const float* __restrict__ bout, float* __restrict__ out, int n) {
    int node = blockIdx.x * 4 + (threadIdx.x >> 6);
    int lane = threadIdx.x & 63;
    if (node >= n) return;
    float4 v = ((const float4*)(h3 + (size_t)node * 256))[lane];
    float4 w = ((const float4*)Wout)[lane];
    float sum = v.x * w.x + v.y * w.y + v.z * w.z + v.w * w.w;
    #pragma unroll
    for (int d = 32; d > 0; d >>= 1) sum += __shfl_down(sum, d, 64);
    if (lane == 0) out[node] = sum + bout[0];
}

extern "C" void kernel_launch(void* const* d_in, const int* in_sizes, int n_in,
                              void* d_out, int out_size, void* d_ws, size_t ws_size,
                              hipStream_t stream) {
    const int n = NN, e = EE;
    const float* x    = (const float*)d_in[0];
    const int*   eidx = (const int*)d_in[1];
    const float* W1   = (const float*)d_in[2];
    const float* b1   = (const float*)d_in[3];
    const float* Wh   = (const float*)d_in[4];
    const float* bh   = (const float*)d_in[5];
    const float* W2   = (const float*)d_in[6];
    const float* b2   = (const float*)d_in[7];
    const float* Wout = (const float*)d_in[8];
    const float* bout = (const float*)d_in[9];
    const int* row = eidx;        // sources
    const int* col = eidx + e;    // destinations

    char* ws = (char*)d_ws;
    int*    cnt     = (int*)ws;    ws += (size_t)n * 4;
    int*    offs    = (int*)ws;    ws += (size_t)n * 4;
    int*    cursor  = (int*)ws;    ws += (size_t)n * 4;
    float*  dinv    = (float*)ws;  ws += (size_t)n * 4;
    int*    bsum    = (int*)ws;    ws += (size_t)256 * 4;
    int2*   pair    = (int2*)ws;   ws += (size_t)e * 8;
    float*  buf     = (float*)ws;  ws += (size_t)n * 256 * 4;   // hidden state [n][256]
    ushort* a2      = (ushort*)ws; ws += (size_t)n * 512 * 2;   // A'' hi|lo [n][512]
    ushort* wt1     = (ushort*)ws; ws += (size_t)256 * 768 * 2;
    ushort* wt2     = (ushort*)ws; ws += (size_t)256 * 768 * 2;
    ushort* wt3     = (ushort*)ws; ws += (size_t)256 * 768 * 2;

    float* outv = (float*)d_out;
    float* h3   = (float*)d_out + n;

    int nb_n = (n + 255) / 256;     // 79
    int nb_e = (e + 255) / 256;

    // CSR build
    init_cnt_kernel<<<nb_n, 256, 0, stream>>>(cnt, n);
    hist_kernel<<<nb_e, 256, 0, stream>>>(col, cnt, e);
    dinv_kernel<<<nb_n, 256, 0, stream>>>(cnt, dinv, n);
    scan_p1_kernel<<<nb_n, 256, 0, stream>>>(cnt, offs, bsum, n);
    scan_p2_kernel<<<1, 256, 0, stream>>>(bsum, nb_n);
    scan_p3_kernel<<<nb_n, 256, 0, stream>>>(offs, bsum, cursor, n);
    scatter_kernel<<<nb_e, 256, 0, stream>>>(row, col, dinv, cursor, pair, e);

    // weight prep
    wprep_kernel<<<256, 256, 0, stream>>>(W1, wt1);
    wprep_kernel<<<256, 256, 0, stream>>>(Wh, wt2);
    wprep_kernel<<<256, 256, 0, stream>>>(W2, wt3);

    int agrid = (n / 32) * 8;          // 5000 blocks: chunk = bid&7, nodegroup = bid>>3
    dim3 ggrid((n + 127) / 128, 2);    // (157, 2)

    // layer 1 (agg reads x directly)
    agg_kernel<<<agrid, 256, 0, stream>>>(x, offs, cnt, pair, dinv, a2, n);
    gemm_mfma_kernel<true><<<ggrid, 256, 0, stream>>>(a2, wt1, b1, buf, n);
    // layer 2
    agg_kernel<<<agrid, 256, 0, stream>>>(buf, offs, cnt, pair, dinv, a2, n);
    gemm_mfma_kernel<true><<<ggrid, 256, 0, stream>>>(a2, wt2, bh, buf, n);
    // layer 3 -> h3 straight into d_out
    agg_kernel<<<agrid, 256, 0, stream>>>(buf, offs, cnt, pair, dinv, a2, n);
    gemm_mfma_kernel<false><<<ggrid, 256, 0, stream>>>(a2, wt3, b2, h3, n);
    // decoder
    out_kernel<<<(n + 3) / 4, 256, 0, stream>>>(h3, Wout, bout, outv, n);
}